// Round 7
// baseline (573.821 us; speedup 1.0000x reference)
//
#include <hip/hip_runtime.h>
#include <math.h>

#define BATCH 32
#define CI 8
#define CO 8
#define KCAP 4
#define DIN 16
#define DOUT 16
#define SS 32
#define HW (SS*SS)          // 1024
#define EPSF 1e-5f

// ---- workspace layout (float element offsets); no votes array anymore ----
#define N_PLANE (BATCH*CO*DOUT*HW)         // 4,194,304 (16.8 MB)
#define OFF_PMAX  0
#define OFF_PMEAN (1*N_PLANE)
#define OFF_ACCM  (2*N_PLANE)
#define OFF_WSUM  (3*N_PLANE)
#define OFF_G     (4*N_PLANE)
#define OFF_CN    (5*N_PLANE)
#define OFF_STATS (6*N_PLANE)
#define ST_BNSUM 0
#define ST_BNSQ  8
#define ST_LNSUM 16
#define ST_LNSQ  272
#define STATS_FLOATS 528

__device__ __forceinline__ void wave_reduce_atomic2(float a, float b, float* da, float* db) {
    #pragma unroll
    for (int off = 32; off > 0; off >>= 1) {
        a += __shfl_down(a, off);
        b += __shfl_down(b, off);
    }
    if ((threadIdx.x & 63) == 0) {
        atomicAdd(da, a);
        atomicAdd(db, b);
    }
}

// ===== Kernel A: fused conv2d + einsum + pool + routing stats ===============
// grid (32, 32): blockIdx.x = q*8 + o (q = 8-row slab 0..3), blockIdx.y = b.
// 256 threads, 1 px each (ul = tid>>5 in 0..7, v = tid&31).
// LDS: caps slab [16 din][10 rows][37] (stride 37 -> 2-way bank = free), 23.7 KB.
// For each d (processed in pairs): conv the 8 ci channels for this (o,d) into
// registers, then reduce over m=kc*8+ci: max/mean (pool) and per-ci mean/std
// (routing). Gate factor (1+s) cancels in softmax -> stats are gate-free.
__global__ __launch_bounds__(256) void convpool_kernel(
        const float* __restrict__ caps, const float* __restrict__ Wt,
        const float* __restrict__ bt, const float* __restrict__ Wv,
        const float* __restrict__ bv,
        float* __restrict__ pmax, float* __restrict__ pmean,
        float* __restrict__ accm_g, float* __restrict__ wsum_g)
{
    __shared__ float xs[DIN * 10 * 37];   // 23,680 B
    const int tid = threadIdx.x;
    const int q = blockIdx.x >> 3;
    const int o = blockIdx.x & 7;
    const int b = blockIdx.y;
    const int r0 = q * 8;                 // first output row of slab

    for (int i = tid; i < DIN * 10 * 37; i += 256) xs[i] = 0.f;
    __syncthreads();
    const float* capb = caps + (size_t)b * DIN * HW;
    #pragma unroll
    for (int it = 0; it < 5; ++it) {
        const int idx = it * 256 + tid;          // 0..1279
        const int din = idx / 80;
        const int rem = idx - din * 80;
        const int row = rem >> 3;                // 0..9
        const int c4 = rem & 7;
        const int gr = r0 - 1 + row;
        if (gr >= 0 && gr < SS) {
            float4 ld = *reinterpret_cast<const float4*>(capb + din * HW + gr * SS + c4 * 4);
            float* dst = &xs[din * 370 + row * 37 + 1 + c4 * 4];
            dst[0] = ld.x; dst[1] = ld.y; dst[2] = ld.z; dst[3] = ld.w;
        }
    }
    __syncthreads();

    const int ul = tid >> 5;              // 0..7
    const int v = tid & 31;
    const int U = r0 + ul;                // global output row

    const float* wv = Wv + (size_t)o * (KCAP * CI) * CI;  // uniform
    const float* bvo = bv + (size_t)o * (KCAP * CI);

    for (int dp = 0; dp < 8; ++dp) {
        const int dbase = dp * 2;
        float acc[CI][2];
        #pragma unroll
        for (int ci = 0; ci < CI; ci++) {
            #pragma unroll
            for (int dj = 0; dj < 2; dj++)
                acc[ci][dj] = bt[(ci * CO + o) * DOUT + dbase + dj];
        }
        for (int din = 0; din < DIN; ++din) {
            float x[3][3];
            #pragma unroll
            for (int r = 0; r < 3; r++)
                #pragma unroll
                for (int c = 0; c < 3; c++)
                    x[r][c] = xs[din * 370 + (ul + r) * 37 + v + c];
            #pragma unroll
            for (int ci = 0; ci < CI; ci++) {
                #pragma unroll
                for (int dj = 0; dj < 2; dj++) {
                    const float* wp = Wt +
                        ((size_t)((ci * CO + o) * DOUT + dbase + dj) * DIN + din) * 9;
                    #pragma unroll
                    for (int ku = 0; ku < 3; ku++)
                        #pragma unroll
                        for (int kv = 0; kv < 3; kv++)
                            acc[ci][dj] += wp[ku * 3 + kv] * x[ku][kv];
                }
            }
        }
        #pragma unroll
        for (int dj = 0; dj < 2; dj++) {
            const int d = dbase + dj;
            float mxv = -1e30f, smv = 0.f, wsv = 0.f, amv = 0.f;
            #pragma unroll
            for (int ci = 0; ci < CI; ci++) {
                float t[KCAP];
                #pragma unroll
                for (int kc = 0; kc < KCAP; kc++) {
                    const int m = kc * CI + ci;
                    float a = bvo[m];
                    #pragma unroll
                    for (int c = 0; c < CI; c++)
                        a += wv[m * CI + c] * acc[c][dj];
                    t[kc] = a;
                    mxv = fmaxf(mxv, a);
                    smv += a;
                }
                float s1 = t[0] + t[1] + t[2] + t[3];
                float s2 = t[0] * t[0] + t[1] * t[1] + t[2] * t[2] + t[3] * t[3];
                float mean_ = s1 * 0.25f;
                float v2_ = fmaxf(s2 * 0.25f - mean_ * mean_, 1e-30f);
                float r_ = rsqrtf(v2_);
                wsv += r_;
                amv += r_ * mean_;
            }
            const size_t gi = (((size_t)b * CO + o) * DOUT + d) * HW + U * SS + v;
            pmax[gi]  = mxv;
            pmean[gi] = smv * (1.f / 32.f);
            accm_g[gi] = amv;
            wsum_g[gi] = wsv;
        }
    }
}

// ===== Kernel B: 3x3x3 stencil over pooled planes + BN partials =============
// grid 1024: blk = b*32 + o*4 + uslab. Block: 8 u-rows x 16 d.
// LDS stride 33 (2 lanes/bank = free). Thread: 4 groups of 4 consecutive v.
__global__ __launch_bounds__(256) void stencil_kernel(
        const float* __restrict__ pmax, const float* __restrict__ pmean,
        const float* __restrict__ Wsp, float* __restrict__ g, float* __restrict__ stats)
{
    __shared__ float smx[DOUT * 10 * 33];   // 21,120 B
    __shared__ float smn[DOUT * 10 * 33];
    const int tid = threadIdx.x;
    const int uslab = blockIdx.x & 3;
    const int o = (blockIdx.x >> 2) & 7;
    const int b = blockIdx.x >> 5;
    const size_t base = ((size_t)(b * CO + o) * DOUT) * HW;

    #pragma unroll
    for (int it = 0; it < 5; ++it) {
        const int idx = it * 256 + tid;          // 0..1279
        const int d = idx / 80;
        const int rem = idx - d * 80;
        const int row = rem >> 3;                // 0..9
        const int c4 = rem & 7;
        const int gu = uslab * 8 - 1 + row;
        float4 vx = make_float4(0.f, 0.f, 0.f, 0.f);
        float4 vn = make_float4(0.f, 0.f, 0.f, 0.f);
        if (gu >= 0 && gu < SS) {
            const size_t off = base + (size_t)d * HW + gu * SS + c4 * 4;
            vx = *reinterpret_cast<const float4*>(pmax + off);
            vn = *reinterpret_cast<const float4*>(pmean + off);
        }
        float* dx = &smx[d * 330 + row * 33 + c4 * 4];
        float* dn = &smn[d * 330 + row * 33 + c4 * 4];
        dx[0] = vx.x; dx[1] = vx.y; dx[2] = vx.z; dx[3] = vx.w;
        dn[0] = vn.x; dn[1] = vn.y; dn[2] = vn.z; dn[3] = vn.w;
    }
    __syncthreads();

    float bnsum = 0.f, bnsq = 0.f;
    #pragma unroll
    for (int it = 0; it < 4; ++it) {
        const int idx = it * 256 + tid;          // 0..1023
        const int d = idx >> 6;
        const int ul = (idx >> 3) & 7;
        const int v4 = (idx & 7) * 4;
        float a0 = 0.f, a1 = 0.f, a2 = 0.f, a3 = 0.f;
        #pragma unroll
        for (int dd = -1; dd <= 1; dd++) {
            const int dpn = d + dd;
            if (dpn < 0 || dpn >= DOUT) continue;
            #pragma unroll
            for (int du = 0; du < 3; du++) {
                const int row = ul + du;         // 0..9 (u halo in LDS)
                const int lb = dpn * 330 + row * 33;
                float cx[6], cn_[6];
                #pragma unroll
                for (int k = 0; k < 6; k++) {
                    const int vv = v4 - 1 + k;
                    const bool ok = (vv >= 0 && vv < SS);
                    cx[k]  = ok ? smx[lb + vv] : 0.f;
                    cn_[k] = ok ? smn[lb + vv] : 0.f;
                }
                const int wb = (dd + 1) * 9 + du * 3;
                #pragma unroll
                for (int dv = 0; dv < 3; dv++) {
                    const float wx = Wsp[wb + dv];
                    const float wn = Wsp[27 + wb + dv];
                    a0 += wx * cx[dv + 0] + wn * cn_[dv + 0];
                    a1 += wx * cx[dv + 1] + wn * cn_[dv + 1];
                    a2 += wx * cx[dv + 2] + wn * cn_[dv + 2];
                    a3 += wx * cx[dv + 3] + wn * cn_[dv + 3];
                }
            }
        }
        const int gu = uslab * 8 + ul;
        *reinterpret_cast<float4*>(&g[base + (size_t)d * HW + gu * SS + v4]) =
            make_float4(a0, a1, a2, a3);
        bnsum += a0 + a1 + a2 + a3;
        bnsq += a0 * a0 + a1 * a1 + a2 * a2 + a3 * a3;
    }
    wave_reduce_atomic2(bnsum, bnsq, &stats[ST_BNSUM + o], &stats[ST_BNSQ + o]);
}

// ===== Kernel C: BN -> sigmoid gate -> caps_next + LN partials ==============
__global__ __launch_bounds__(256) void finalize_kernel(
        const float* __restrict__ g, const float* __restrict__ accm_g,
        const float* __restrict__ wsum_g,
        const float* __restrict__ bn_gamma, const float* __restrict__ bn_beta,
        float* __restrict__ cn, float* __restrict__ stats)
{
    const int d = blockIdx.x & 15;
    const int o = (blockIdx.x >> 4) & 7;
    const int b = blockIdx.x >> 7;
    const int px0 = threadIdx.x * 4;

    const float nbn = 1.f / (float)(BATCH * DOUT * HW);
    const float mu = stats[ST_BNSUM + o] * nbn;
    const float var = fmaxf(stats[ST_BNSQ + o] * nbn - mu * mu, 0.f);
    const float rstd = rsqrtf(var + EPSF);
    const float gam = bn_gamma[0], bet = bn_beta[0];

    const size_t gbase = (((size_t)b * CO + o) * DOUT + d) * HW + px0;
    float4 g4 = *reinterpret_cast<const float4*>(&g[gbase]);
    float4 a4 = *reinterpret_cast<const float4*>(&accm_g[gbase]);
    float4 w4 = *reinterpret_cast<const float4*>(&wsum_g[gbase]);
    float4 cnv;
    cnv.x = (1.f + 1.f / (1.f + expf(-((g4.x - mu) * rstd * gam + bet)))) * a4.x / w4.x;
    cnv.y = (1.f + 1.f / (1.f + expf(-((g4.y - mu) * rstd * gam + bet)))) * a4.y / w4.y;
    cnv.z = (1.f + 1.f / (1.f + expf(-((g4.z - mu) * rstd * gam + bet)))) * a4.z / w4.z;
    cnv.w = (1.f + 1.f / (1.f + expf(-((g4.w - mu) * rstd * gam + bet)))) * a4.w / w4.w;
    *reinterpret_cast<float4*>(&cn[gbase]) = cnv;

    float s = cnv.x + cnv.y + cnv.z + cnv.w;
    float sq = cnv.x * cnv.x + cnv.y * cnv.y + cnv.z * cnv.z + cnv.w * cnv.w;
    wave_reduce_atomic2(s, sq, &stats[ST_LNSUM + b * CO + o], &stats[ST_LNSQ + b * CO + o]);
}

// ===== Kernel D: LayerNorm + transpose-out ==================================
__global__ __launch_bounds__(256) void ln_kernel(
        const float* __restrict__ cn, const float* __restrict__ stats,
        const float* __restrict__ lng, const float* __restrict__ lnb,
        float* __restrict__ out)
{
    const int bo = blockIdx.x;
    const int b = bo >> 3, o = bo & 7;
    const float nln = 1.f / 16384.f;
    const float mu = stats[ST_LNSUM + bo] * nln;
    const float var = fmaxf(stats[ST_LNSQ + bo] * nln - mu * mu, 0.f);
    const float rstd = rsqrtf(var + EPSF);
    const float* src = cn + (size_t)bo * 16384;
    float* dst = out + ((size_t)o * BATCH + b) * 16384;
    #pragma unroll
    for (int i = 0; i < 16; i++) {
        const int e = i * 1024 + threadIdx.x * 4;
        float4 x = *reinterpret_cast<const float4*>(src + e);
        float4 gm = *reinterpret_cast<const float4*>(lng + e);
        float4 bb = *reinterpret_cast<const float4*>(lnb + e);
        float4 y;
        y.x = (x.x - mu) * rstd * gm.x + bb.x;
        y.y = (x.y - mu) * rstd * gm.y + bb.y;
        y.z = (x.z - mu) * rstd * gm.z + bb.z;
        y.w = (x.w - mu) * rstd * gm.w + bb.w;
        *reinterpret_cast<float4*>(dst + e) = y;
    }
}

extern "C" void kernel_launch(void* const* d_in, const int* in_sizes, int n_in,
                              void* d_out, int out_size, void* d_ws, size_t ws_size,
                              hipStream_t stream) {
    const float* caps = (const float*)d_in[0];
    const float* Wt   = (const float*)d_in[1];
    const float* bt   = (const float*)d_in[2];
    const float* Wv   = (const float*)d_in[3];
    const float* bv   = (const float*)d_in[4];
    const float* Wsp  = (const float*)d_in[5];
    const float* bng  = (const float*)d_in[6];
    const float* bnb  = (const float*)d_in[7];
    const float* lng  = (const float*)d_in[8];
    const float* lnb  = (const float*)d_in[9];
    float* ws = (float*)d_ws;
    float* pmax  = ws + OFF_PMAX;
    float* pmean = ws + OFF_PMEAN;
    float* accm  = ws + OFF_ACCM;
    float* wsum  = ws + OFF_WSUM;
    float* g     = ws + OFF_G;
    float* cn    = ws + OFF_CN;
    float* stats = ws + OFF_STATS;
    float* out = (float*)d_out;

    hipMemsetAsync(stats, 0, STATS_FLOATS * sizeof(float), stream);
    convpool_kernel<<<dim3(32, 32), 256, 0, stream>>>(caps, Wt, bt, Wv, bv,
                                                      pmax, pmean, accm, wsum);
    stencil_kernel<<<1024, 256, 0, stream>>>(pmax, pmean, Wsp, g, stats);
    finalize_kernel<<<4096, 256, 0, stream>>>(g, accm, wsum, bng, bnb, cn, stats);
    ln_kernel<<<256, 256, 0, stream>>>(cn, stats, lng, lnb, out);
}

// Round 8
// 303.696 us; speedup vs baseline: 1.8895x; 1.8895x over previous
//
#include <hip/hip_runtime.h>
#include <math.h>

#define BATCH 32
#define CI 8
#define CO 8
#define KCAP 4
#define DIN 16
#define DOUT 16
#define SS 32
#define HW (SS*SS)          // 1024
#define EPSF 1e-5f

// ---- workspace layout (float element offsets) ----
#define N_PLANE (BATCH*CO*DOUT*HW)         // 4,194,304 (16.8 MB)
#define OFF_PMAX  0
#define OFF_PMEAN (1*N_PLANE)
#define OFF_ACCM  (2*N_PLANE)
#define OFF_WSUM  (3*N_PLANE)
#define OFF_G     (4*N_PLANE)
#define OFF_CN    (5*N_PLANE)
#define OFF_STATS (6*N_PLANE)
#define ST_BNSUM 0
#define ST_BNSQ  8
#define ST_LNSUM 16
#define ST_LNSQ  272
#define STATS_FLOATS 528
#define OFF_WFRAG (OFF_STATS + STATS_FLOATS)   // ushort[655360] = 1.31 MB

typedef __attribute__((ext_vector_type(8))) short bf16x8;
typedef __attribute__((ext_vector_type(16))) float f32x16;

__device__ __forceinline__ ushort f2bf(float f) {
    unsigned u = __float_as_uint(f);
    unsigned r = (u + 0x7FFFu + ((u >> 16) & 1u)) >> 16;
    return (ushort)r;
}

__device__ __forceinline__ void wave_reduce_atomic2(float a, float b, float* da, float* db) {
    #pragma unroll
    for (int off = 32; off > 0; off >>= 1) {
        a += __shfl_down(a, off);
        b += __shfl_down(b, off);
    }
    if ((threadIdx.x & 63) == 0) {
        atomicAdd(da, a);
        atomicAdd(db, b);
    }
}

// ===== Kernel 0: combined-weight fragments =================================
// W_comb[o,d][m][k] = sum_ci Wv[o][m][ci] * Wt[(ci*8+o)*16+d][din][ku][kv],
// k = tap*16+din (tap=ku*3+kv); k=144 holds the combined bias (bias trick:
// B-side supplies a constant-1.0 plane at tap 9); k=145..159 zero.
// Stored bf16 in MFMA A-frag order: [o][d][kk=0..9][lane][e=0..7],
// slot (lane,e) -> m = lane&31, k = kk*16 + (lane>>5)*8 + e.
__global__ __launch_bounds__(256) void wfrag_kernel(
        const float* __restrict__ Wt, const float* __restrict__ bt,
        const float* __restrict__ Wv, const float* __restrict__ bv,
        ushort* __restrict__ wfrag)
{
    const int idx = blockIdx.x * 256 + threadIdx.x;   // 0..81919
    const int lane = idx & 63;
    const int kk = (idx >> 6) % 10;
    const int d = (idx / 640) & 15;
    const int o = idx / 10240;
    const int m = lane & 31;
    ushort outv[8];
    #pragma unroll
    for (int e = 0; e < 8; ++e) {
        const int k = kk * 16 + (lane >> 5) * 8 + e;
        float w = 0.f;
        if (k < 144) {
            const int tap = k >> 4;      // == kk
            const int din = k & 15;
            #pragma unroll
            for (int ci = 0; ci < 8; ++ci)
                w += Wv[(o * 32 + m) * 8 + ci] *
                     Wt[((size_t)((ci * 8 + o) * 16 + d) * 16 + din) * 9 + tap];
        } else if (k == 144) {
            w = bv[o * 32 + m];
            #pragma unroll
            for (int ci = 0; ci < 8; ++ci)
                w += Wv[(o * 32 + m) * 8 + ci] * bt[(ci * 8 + o) * 16 + d];
        }
        outv[e] = f2bf(w);
    }
    uint4 st;
    st.x = (unsigned)outv[0] | ((unsigned)outv[1] << 16);
    st.y = (unsigned)outv[2] | ((unsigned)outv[3] << 16);
    st.z = (unsigned)outv[4] | ((unsigned)outv[5] << 16);
    st.w = (unsigned)outv[6] | ((unsigned)outv[7] << 16);
    *reinterpret_cast<uint4*>(wfrag + (size_t)idx * 8) = st;
}

// ===== Kernel 1: MFMA conv+einsum+pool+routing stats ========================
// grid (16, 32): blockIdx.x = o*2+dh, blockIdx.y = b. 256 thr = 4 waves.
// LDS: caps as bf16 [row 34][col 34][din-slot 24] (halo-padded; slot 16 = 1.0
// bias plane, 17..23 = 0). 55,488 B. v-stride 48 B = 3 superbanks (coprime 8)
// -> conflict-free ds_read_b128 B-fragments with compile-time tap offsets.
// Per d: values[32m][1024px] = W_comb @ B, then per px: pool max/mean over m,
// routing stats per ci over kc (C-layout gives lane all 4 kc of 4 ci's).
__global__ __launch_bounds__(256) void convmfma_kernel(
        const float* __restrict__ caps, const ushort* __restrict__ wfrag,
        float* __restrict__ pmax, float* __restrict__ pmean,
        float* __restrict__ accm_g, float* __restrict__ wsum_g)
{
    __shared__ __align__(16) ushort xs[34 * 34 * 24];   // 55,488 B
    const int tid = threadIdx.x;
    const int o = blockIdx.x >> 1;
    const int dh = blockIdx.x & 1;
    const int b = blockIdx.y;

    // zero-fill
    for (int i = tid; i < 34 * 34 * 24 / 4; i += 256)
        reinterpret_cast<uint2*>(xs)[i] = make_uint2(0u, 0u);
    __syncthreads();
    // bias-plane ones at [r][c][16] for r,c in 0..31 (tap-9 cells)
    for (int i = tid; i < 1024; i += 256) {
        const int r = i >> 5, c = i & 31;
        xs[(r * 34 + c) * 24 + 16] = 0x3F80;
    }
    // data fill: input row u -> storage row u+1, col v -> v+1, din slot 0..15
    const float* capb = caps + (size_t)b * DIN * HW;
    {
        const int u = tid >> 3, v0 = (tid & 7) * 4;
        #pragma unroll
        for (int din = 0; din < DIN; ++din) {
            float4 ld = *reinterpret_cast<const float4*>(capb + din * HW + tid * 4);
            xs[((u + 1) * 34 + (v0 + 1)) * 24 + din] = f2bf(ld.x);
            xs[((u + 1) * 34 + (v0 + 2)) * 24 + din] = f2bf(ld.y);
            xs[((u + 1) * 34 + (v0 + 3)) * 24 + din] = f2bf(ld.z);
            xs[((u + 1) * 34 + (v0 + 4)) * 24 + din] = f2bf(ld.w);
        }
    }
    __syncthreads();

    const int l = tid & 63;
    const int wv = tid >> 6;
    const int lg = l >> 5;
    const int v = l & 31;
    const bf16x8* wf = reinterpret_cast<const bf16x8*>(wfrag);
    // byte offsets per k-step: tap (ku,kv): (ku*34+kv)*48; tap9 (bias) -> +32
    constexpr int OFFS[10] = {0, 48, 96, 1632, 1680, 1728, 3264, 3312, 3360, 32};

    for (int dp = 0; dp < 4; ++dp) {
        const int d0 = dh * 8 + dp * 2, d1 = d0 + 1;
        bf16x8 af0[10], af1[10];
        #pragma unroll
        for (int kk = 0; kk < 10; ++kk) {
            af0[kk] = wf[(size_t)((o * 16 + d0) * 10 + kk) * 64 + l];
            af1[kk] = wf[(size_t)((o * 16 + d1) * 10 + kk) * 64 + l];
        }
        for (int nt = 0; nt < 8; ++nt) {
            const int u = wv * 8 + nt;
            const int baddr = (u * 34 + v) * 48 + lg * 16;
            f32x16 c0, c1;
            #pragma unroll
            for (int i = 0; i < 16; ++i) { c0[i] = 0.f; c1[i] = 0.f; }
            #pragma unroll
            for (int kk = 0; kk < 10; ++kk) {
                bf16x8 bb = *reinterpret_cast<const bf16x8*>(
                    reinterpret_cast<const char*>(xs) + baddr + OFFS[kk]);
                c0 = __builtin_amdgcn_mfma_f32_32x32x16_bf16(af0[kk], bb, c0, 0, 0, 0);
                c1 = __builtin_amdgcn_mfma_f32_32x32x16_bf16(af1[kk], bb, c1, 0, 0, 0);
            }
            const int px = u * 32 + v;
            #pragma unroll
            for (int half = 0; half < 2; ++half) {
                const f32x16 c = half ? c1 : c0;
                const int d = half ? d1 : d0;
                const size_t idx = ((size_t)(b * 8 + o) * 16 + d) * 1024 + px;
                // C/D layout (m74/m101): row m = (r&3)+8*(r>>2)+4*(l>>5)
                // -> lane regs r = kc*4+cil hold kc=r>>2, ci=(r&3)+4*(l>>5)
                float vmax = c[0], vsum = c[0];
                #pragma unroll
                for (int r = 1; r < 16; ++r) { vmax = fmaxf(vmax, c[r]); vsum += c[r]; }
                float wsp = 0.f, amp = 0.f;
                #pragma unroll
                for (int cil = 0; cil < 4; ++cil) {
                    float t0 = c[cil], t1 = c[cil + 4], t2 = c[cil + 8], t3 = c[cil + 12];
                    float s1 = t0 + t1 + t2 + t3;
                    float s2 = t0 * t0 + t1 * t1 + t2 * t2 + t3 * t3;
                    float mean = 0.25f * s1;
                    float var = fmaxf(0.25f * s2 - mean * mean, 1e-30f);
                    float rq = rsqrtf(var);
                    wsp += rq; amp += rq * mean;
                }
                vmax = fmaxf(vmax, __shfl_xor(vmax, 32));
                vsum += __shfl_xor(vsum, 32);
                wsp += __shfl_xor(wsp, 32);
                amp += __shfl_xor(amp, 32);
                if (l < 32) { pmax[idx] = vmax; accm_g[idx] = amp; }
                else        { pmean[idx] = vsum * (1.f / 32.f); wsum_g[idx] = wsp; }
            }
        }
    }
}

// ===== Kernel 2: 3x3x3 stencil over pooled planes + BN partials (proven) ====
__global__ __launch_bounds__(256) void stencil_kernel(
        const float* __restrict__ pmax, const float* __restrict__ pmean,
        const float* __restrict__ Wsp, float* __restrict__ g, float* __restrict__ stats)
{
    __shared__ float smx[DOUT * 10 * 33];
    __shared__ float smn[DOUT * 10 * 33];
    const int tid = threadIdx.x;
    const int uslab = blockIdx.x & 3;
    const int o = (blockIdx.x >> 2) & 7;
    const int b = blockIdx.x >> 5;
    const size_t base = ((size_t)(b * CO + o) * DOUT) * HW;

    #pragma unroll
    for (int it = 0; it < 5; ++it) {
        const int idx = it * 256 + tid;
        const int d = idx / 80;
        const int rem = idx - d * 80;
        const int row = rem >> 3;
        const int c4 = rem & 7;
        const int gu = uslab * 8 - 1 + row;
        float4 vx = make_float4(0.f, 0.f, 0.f, 0.f);
        float4 vn = make_float4(0.f, 0.f, 0.f, 0.f);
        if (gu >= 0 && gu < SS) {
            const size_t off = base + (size_t)d * HW + gu * SS + c4 * 4;
            vx = *reinterpret_cast<const float4*>(pmax + off);
            vn = *reinterpret_cast<const float4*>(pmean + off);
        }
        float* dx = &smx[d * 330 + row * 33 + c4 * 4];
        float* dn = &smn[d * 330 + row * 33 + c4 * 4];
        dx[0] = vx.x; dx[1] = vx.y; dx[2] = vx.z; dx[3] = vx.w;
        dn[0] = vn.x; dn[1] = vn.y; dn[2] = vn.z; dn[3] = vn.w;
    }
    __syncthreads();

    float bnsum = 0.f, bnsq = 0.f;
    #pragma unroll
    for (int it = 0; it < 4; ++it) {
        const int idx = it * 256 + tid;
        const int d = idx >> 6;
        const int ul = (idx >> 3) & 7;
        const int v4 = (idx & 7) * 4;
        float a0 = 0.f, a1 = 0.f, a2 = 0.f, a3 = 0.f;
        #pragma unroll
        for (int dd = -1; dd <= 1; dd++) {
            const int dpn = d + dd;
            if (dpn < 0 || dpn >= DOUT) continue;
            #pragma unroll
            for (int du = 0; du < 3; du++) {
                const int row = ul + du;
                const int lb = dpn * 330 + row * 33;
                float cx[6], cn_[6];
                #pragma unroll
                for (int k = 0; k < 6; k++) {
                    const int vv = v4 - 1 + k;
                    const bool ok = (vv >= 0 && vv < SS);
                    cx[k]  = ok ? smx[lb + vv] : 0.f;
                    cn_[k] = ok ? smn[lb + vv] : 0.f;
                }
                const int wb = (dd + 1) * 9 + du * 3;
                #pragma unroll
                for (int dv = 0; dv < 3; dv++) {
                    const float wx = Wsp[wb + dv];
                    const float wn = Wsp[27 + wb + dv];
                    a0 += wx * cx[dv + 0] + wn * cn_[dv + 0];
                    a1 += wx * cx[dv + 1] + wn * cn_[dv + 1];
                    a2 += wx * cx[dv + 2] + wn * cn_[dv + 2];
                    a3 += wx * cx[dv + 3] + wn * cn_[dv + 3];
                }
            }
        }
        const int gu = uslab * 8 + ul;
        *reinterpret_cast<float4*>(&g[base + (size_t)d * HW + gu * SS + v4]) =
            make_float4(a0, a1, a2, a3);
        bnsum += a0 + a1 + a2 + a3;
        bnsq += a0 * a0 + a1 * a1 + a2 * a2 + a3 * a3;
    }
    wave_reduce_atomic2(bnsum, bnsq, &stats[ST_BNSUM + o], &stats[ST_BNSQ + o]);
}

// ===== Kernel 3: BN -> sigmoid gate -> caps_next + LN partials (proven) =====
__global__ __launch_bounds__(256) void finalize_kernel(
        const float* __restrict__ g, const float* __restrict__ accm_g,
        const float* __restrict__ wsum_g,
        const float* __restrict__ bn_gamma, const float* __restrict__ bn_beta,
        float* __restrict__ cn, float* __restrict__ stats)
{
    const int d = blockIdx.x & 15;
    const int o = (blockIdx.x >> 4) & 7;
    const int b = blockIdx.x >> 7;
    const int px0 = threadIdx.x * 4;

    const float nbn = 1.f / (float)(BATCH * DOUT * HW);
    const float mu = stats[ST_BNSUM + o] * nbn;
    const float var = fmaxf(stats[ST_BNSQ + o] * nbn - mu * mu, 0.f);
    const float rstd = rsqrtf(var + EPSF);
    const float gam = bn_gamma[0], bet = bn_beta[0];

    const size_t gbase = (((size_t)b * CO + o) * DOUT + d) * HW + px0;
    float4 g4 = *reinterpret_cast<const float4*>(&g[gbase]);
    float4 a4 = *reinterpret_cast<const float4*>(&accm_g[gbase]);
    float4 w4 = *reinterpret_cast<const float4*>(&wsum_g[gbase]);
    float4 cnv;
    cnv.x = (1.f + 1.f / (1.f + expf(-((g4.x - mu) * rstd * gam + bet)))) * a4.x / w4.x;
    cnv.y = (1.f + 1.f / (1.f + expf(-((g4.y - mu) * rstd * gam + bet)))) * a4.y / w4.y;
    cnv.z = (1.f + 1.f / (1.f + expf(-((g4.z - mu) * rstd * gam + bet)))) * a4.z / w4.z;
    cnv.w = (1.f + 1.f / (1.f + expf(-((g4.w - mu) * rstd * gam + bet)))) * a4.w / w4.w;
    *reinterpret_cast<float4*>(&cn[gbase]) = cnv;

    float s = cnv.x + cnv.y + cnv.z + cnv.w;
    float sq = cnv.x * cnv.x + cnv.y * cnv.y + cnv.z * cnv.z + cnv.w * cnv.w;
    wave_reduce_atomic2(s, sq, &stats[ST_LNSUM + b * CO + o], &stats[ST_LNSQ + b * CO + o]);
}

// ===== Kernel 4: LayerNorm + transpose-out (proven) =========================
__global__ __launch_bounds__(256) void ln_kernel(
        const float* __restrict__ cn, const float* __restrict__ stats,
        const float* __restrict__ lng, const float* __restrict__ lnb,
        float* __restrict__ out)
{
    const int bo = blockIdx.x;
    const int b = bo >> 3, o = bo & 7;
    const float nln = 1.f / 16384.f;
    const float mu = stats[ST_LNSUM + bo] * nln;
    const float var = fmaxf(stats[ST_LNSQ + bo] * nln - mu * mu, 0.f);
    const float rstd = rsqrtf(var + EPSF);
    const float* src = cn + (size_t)bo * 16384;
    float* dst = out + ((size_t)o * BATCH + b) * 16384;
    #pragma unroll
    for (int i = 0; i < 16; i++) {
        const int e = i * 1024 + threadIdx.x * 4;
        float4 x = *reinterpret_cast<const float4*>(src + e);
        float4 gm = *reinterpret_cast<const float4*>(lng + e);
        float4 bb = *reinterpret_cast<const float4*>(lnb + e);
        float4 y;
        y.x = (x.x - mu) * rstd * gm.x + bb.x;
        y.y = (x.y - mu) * rstd * gm.y + bb.y;
        y.z = (x.z - mu) * rstd * gm.z + bb.z;
        y.w = (x.w - mu) * rstd * gm.w + bb.w;
        *reinterpret_cast<float4*>(dst + e) = y;
    }
}

extern "C" void kernel_launch(void* const* d_in, const int* in_sizes, int n_in,
                              void* d_out, int out_size, void* d_ws, size_t ws_size,
                              hipStream_t stream) {
    const float* caps = (const float*)d_in[0];
    const float* Wt   = (const float*)d_in[1];
    const float* bt   = (const float*)d_in[2];
    const float* Wv   = (const float*)d_in[3];
    const float* bv   = (const float*)d_in[4];
    const float* Wsp  = (const float*)d_in[5];
    const float* bng  = (const float*)d_in[6];
    const float* bnb  = (const float*)d_in[7];
    const float* lng  = (const float*)d_in[8];
    const float* lnb  = (const float*)d_in[9];
    float* ws = (float*)d_ws;
    float* pmax  = ws + OFF_PMAX;
    float* pmean = ws + OFF_PMEAN;
    float* accm  = ws + OFF_ACCM;
    float* wsum  = ws + OFF_WSUM;
    float* g     = ws + OFF_G;
    float* cn    = ws + OFF_CN;
    float* stats = ws + OFF_STATS;
    ushort* wfrag = (ushort*)(ws + OFF_WFRAG);
    float* out = (float*)d_out;

    hipMemsetAsync(stats, 0, STATS_FLOATS * sizeof(float), stream);
    wfrag_kernel<<<320, 256, 0, stream>>>(Wt, bt, Wv, bv, wfrag);
    convmfma_kernel<<<dim3(16, 32), 256, 0, stream>>>(caps, wfrag, pmax, pmean, accm, wsum);
    stencil_kernel<<<1024, 256, 0, stream>>>(pmax, pmean, Wsp, g, stats);
    finalize_kernel<<<4096, 256, 0, stream>>>(g, accm, wsum, bng, bnb, cn, stats);
    ln_kernel<<<256, 256, 0, stream>>>(cn, stats, lng, lnb, out);
}

// Round 9
// 213.149 us; speedup vs baseline: 2.6921x; 1.4248x over previous
//
#include <hip/hip_runtime.h>
#include <math.h>

#define BATCH 32
#define CI 8
#define CO 8
#define KCAP 4
#define DIN 16
#define DOUT 16
#define SS 32
#define HW (SS*SS)          // 1024
#define EPSF 1e-5f

// ---- workspace layout (float element offsets) ----
#define N_PLANE (BATCH*CO*DOUT*HW)         // 4,194,304 (16.8 MB)
#define OFF_PMAX  0
#define OFF_PMEAN (1*N_PLANE)
#define OFF_ACCM  (2*N_PLANE)
#define OFF_WSUM  (3*N_PLANE)
#define OFF_G     (4*N_PLANE)
#define OFF_CN    (5*N_PLANE)
#define OFF_STATS (6*N_PLANE)
#define ST_BNSUM 0
#define ST_BNSQ  8
#define ST_LNSUM 16
#define ST_LNSQ  272
#define STATS_FLOATS 528
#define OFF_WFRAG (OFF_STATS + STATS_FLOATS)   // ushort[655360] = 1.31 MB

typedef __attribute__((ext_vector_type(8))) short bf16x8;
typedef __attribute__((ext_vector_type(16))) float f32x16;

__device__ __forceinline__ ushort f2bf(float f) {
    unsigned u = __float_as_uint(f);
    unsigned r = (u + 0x7FFFu + ((u >> 16) & 1u)) >> 16;
    return (ushort)r;
}

__device__ __forceinline__ void wave_reduce_atomic2(float a, float b, float* da, float* db) {
    #pragma unroll
    for (int off = 32; off > 0; off >>= 1) {
        a += __shfl_down(a, off);
        b += __shfl_down(b, off);
    }
    if ((threadIdx.x & 63) == 0) {
        atomicAdd(da, a);
        atomicAdd(db, b);
    }
}

// ===== Kernel 0: combined-weight fragments (proven r8) ======================
__global__ __launch_bounds__(256) void wfrag_kernel(
        const float* __restrict__ Wt, const float* __restrict__ bt,
        const float* __restrict__ Wv, const float* __restrict__ bv,
        ushort* __restrict__ wfrag)
{
    const int idx = blockIdx.x * 256 + threadIdx.x;   // 0..81919
    const int lane = idx & 63;
    const int kk = (idx >> 6) % 10;
    const int d = (idx / 640) & 15;
    const int o = idx / 10240;
    const int m = lane & 31;
    ushort outv[8];
    #pragma unroll
    for (int e = 0; e < 8; ++e) {
        const int k = kk * 16 + (lane >> 5) * 8 + e;
        float w = 0.f;
        if (k < 144) {
            const int tap = k >> 4;      // == kk
            const int din = k & 15;
            #pragma unroll
            for (int ci = 0; ci < 8; ++ci)
                w += Wv[(o * 32 + m) * 8 + ci] *
                     Wt[((size_t)((ci * 8 + o) * 16 + d) * 16 + din) * 9 + tap];
        } else if (k == 144) {
            w = bv[o * 32 + m];
            #pragma unroll
            for (int ci = 0; ci < 8; ++ci)
                w += Wv[(o * 32 + m) * 8 + ci] * bt[(ci * 8 + o) * 16 + d];
        }
        outv[e] = f2bf(w);
    }
    uint4 st;
    st.x = (unsigned)outv[0] | ((unsigned)outv[1] << 16);
    st.y = (unsigned)outv[2] | ((unsigned)outv[3] << 16);
    st.z = (unsigned)outv[4] | ((unsigned)outv[5] << 16);
    st.w = (unsigned)outv[6] | ((unsigned)outv[7] << 16);
    *reinterpret_cast<uint4*>(wfrag + (size_t)idx * 8) = st;
}

// ===== Kernel 1: MFMA conv+einsum+pool+routing stats (proven r8) ============
__global__ __launch_bounds__(256) void convmfma_kernel(
        const float* __restrict__ caps, const ushort* __restrict__ wfrag,
        float* __restrict__ pmax, float* __restrict__ pmean,
        float* __restrict__ accm_g, float* __restrict__ wsum_g)
{
    __shared__ __align__(16) ushort xs[34 * 34 * 24];   // 55,488 B
    const int tid = threadIdx.x;
    const int o = blockIdx.x >> 1;
    const int dh = blockIdx.x & 1;
    const int b = blockIdx.y;

    for (int i = tid; i < 34 * 34 * 24 / 4; i += 256)
        reinterpret_cast<uint2*>(xs)[i] = make_uint2(0u, 0u);
    __syncthreads();
    for (int i = tid; i < 1024; i += 256) {
        const int r = i >> 5, c = i & 31;
        xs[(r * 34 + c) * 24 + 16] = 0x3F80;
    }
    const float* capb = caps + (size_t)b * DIN * HW;
    {
        const int u = tid >> 3, v0 = (tid & 7) * 4;
        #pragma unroll
        for (int din = 0; din < DIN; ++din) {
            float4 ld = *reinterpret_cast<const float4*>(capb + din * HW + tid * 4);
            xs[((u + 1) * 34 + (v0 + 1)) * 24 + din] = f2bf(ld.x);
            xs[((u + 1) * 34 + (v0 + 2)) * 24 + din] = f2bf(ld.y);
            xs[((u + 1) * 34 + (v0 + 3)) * 24 + din] = f2bf(ld.z);
            xs[((u + 1) * 34 + (v0 + 4)) * 24 + din] = f2bf(ld.w);
        }
    }
    __syncthreads();

    const int l = tid & 63;
    const int wv = tid >> 6;
    const int lg = l >> 5;
    const int v = l & 31;
    const bf16x8* wf = reinterpret_cast<const bf16x8*>(wfrag);
    constexpr int OFFS[10] = {0, 48, 96, 1632, 1680, 1728, 3264, 3312, 3360, 32};

    for (int dp = 0; dp < 4; ++dp) {
        const int d0 = dh * 8 + dp * 2, d1 = d0 + 1;
        bf16x8 af0[10], af1[10];
        #pragma unroll
        for (int kk = 0; kk < 10; ++kk) {
            af0[kk] = wf[(size_t)((o * 16 + d0) * 10 + kk) * 64 + l];
            af1[kk] = wf[(size_t)((o * 16 + d1) * 10 + kk) * 64 + l];
        }
        for (int nt = 0; nt < 8; ++nt) {
            const int u = wv * 8 + nt;
            const int baddr = (u * 34 + v) * 48 + lg * 16;
            f32x16 c0, c1;
            #pragma unroll
            for (int i = 0; i < 16; ++i) { c0[i] = 0.f; c1[i] = 0.f; }
            #pragma unroll
            for (int kk = 0; kk < 10; ++kk) {
                bf16x8 bb = *reinterpret_cast<const bf16x8*>(
                    reinterpret_cast<const char*>(xs) + baddr + OFFS[kk]);
                c0 = __builtin_amdgcn_mfma_f32_32x32x16_bf16(af0[kk], bb, c0, 0, 0, 0);
                c1 = __builtin_amdgcn_mfma_f32_32x32x16_bf16(af1[kk], bb, c1, 0, 0, 0);
            }
            const int px = u * 32 + v;
            #pragma unroll
            for (int half = 0; half < 2; ++half) {
                const f32x16 c = half ? c1 : c0;
                const int d = half ? d1 : d0;
                const size_t idx = ((size_t)(b * 8 + o) * 16 + d) * 1024 + px;
                float vmax = c[0], vsum = c[0];
                #pragma unroll
                for (int r = 1; r < 16; ++r) { vmax = fmaxf(vmax, c[r]); vsum += c[r]; }
                float wsp = 0.f, amp = 0.f;
                #pragma unroll
                for (int cil = 0; cil < 4; ++cil) {
                    float t0 = c[cil], t1 = c[cil + 4], t2 = c[cil + 8], t3 = c[cil + 12];
                    float s1 = t0 + t1 + t2 + t3;
                    float s2 = t0 * t0 + t1 * t1 + t2 * t2 + t3 * t3;
                    float mean = 0.25f * s1;
                    float var = fmaxf(0.25f * s2 - mean * mean, 1e-30f);
                    float rq = rsqrtf(var);
                    wsp += rq; amp += rq * mean;
                }
                vmax = fmaxf(vmax, __shfl_xor(vmax, 32));
                vsum += __shfl_xor(vsum, 32);
                wsp += __shfl_xor(wsp, 32);
                amp += __shfl_xor(amp, 32);
                if (l < 32) { pmax[idx] = vmax; accm_g[idx] = amp; }
                else        { pmean[idx] = vsum * (1.f / 32.f); wsum_g[idx] = wsp; }
            }
        }
    }
}

// ===== Kernel 2: d-marching 3x3x3 stencil + BN partials (REWRITTEN) =========
// grid 256: blk = b*8 + o. 256 threads: u = tid>>3, v4 = (tid&7)*4 (4 px).
// LDS ring: 2 slots x {pmax,pmean} plane [34 rows][40 cols], data col v -> v+4
// (aligned b128 window), halo rows/cols stay zero. Plane p arriving adds
// W[2]->out[p-1], W[1]->out[p], W[0]->out[p+1] (3 rolling float4 accs).
// Each plane read from global exactly once; 1 sync/iter; 1 atomic pair/block.
__global__ __launch_bounds__(256) void stencil_kernel(
        const float* __restrict__ pmax, const float* __restrict__ pmean,
        const float* __restrict__ Wsp, float* __restrict__ g, float* __restrict__ stats)
{
    __shared__ float sm[2][2][34 * 40];   // 21,760 B
    __shared__ float red[8];
    const int tid = threadIdx.x;
    const int o = blockIdx.x & 7;
    const int b = blockIdx.x >> 3;
    const int u = tid >> 3;
    const int v4 = (tid & 7) * 4;
    const size_t base = ((size_t)(b * CO + o) * DOUT) * HW;
    const int prow = u * SS + v4;

    for (int i = tid; i < 2 * 2 * 34 * 40; i += 256) (&sm[0][0][0])[i] = 0.f;
    float4 ldx = *reinterpret_cast<const float4*>(pmax + base + prow);
    float4 ldn = *reinterpret_cast<const float4*>(pmean + base + prow);
    __syncthreads();
    *reinterpret_cast<float4*>(&sm[0][0][(u + 1) * 40 + v4 + 4]) = ldx;
    *reinterpret_cast<float4*>(&sm[0][1][(u + 1) * 40 + v4 + 4]) = ldn;
    __syncthreads();

    float4 A0 = make_float4(0.f, 0.f, 0.f, 0.f);
    float4 A1 = make_float4(0.f, 0.f, 0.f, 0.f);
    float bnsum = 0.f, bnsq = 0.f;

    for (int p = 0; p < 16; ++p) {
        const int slot = p & 1;
        float4 nx, nn;
        if (p < 15) {   // issue next-plane loads early (latency hides under FMA)
            nx = *reinterpret_cast<const float4*>(pmax + base + (size_t)(p + 1) * HW + prow);
            nn = *reinterpret_cast<const float4*>(pmean + base + (size_t)(p + 1) * HW + prow);
        }
        float4 A2 = make_float4(0.f, 0.f, 0.f, 0.f);
        #pragma unroll
        for (int a = 0; a < 2; ++a) {
            const float* sp = sm[slot][a];
            #pragma unroll
            for (int du = 0; du < 3; ++du) {
                const int rb = (u + du) * 40;
                const float w0 = sp[rb + v4 + 3];
                const float4 m4 = *reinterpret_cast<const float4*>(&sp[rb + v4 + 4]);
                const float w5 = sp[rb + v4 + 8];
                const float w1 = m4.x, w2 = m4.y, w3 = m4.z, w4 = m4.w;
                const int wb = a * 27 + du * 3;
                {   // out[p-1]: dz=+1 -> weight block 2
                    const float c0 = Wsp[wb + 18], c1 = Wsp[wb + 19], c2 = Wsp[wb + 20];
                    A0.x += c0 * w0 + c1 * w1 + c2 * w2;
                    A0.y += c0 * w1 + c1 * w2 + c2 * w3;
                    A0.z += c0 * w2 + c1 * w3 + c2 * w4;
                    A0.w += c0 * w3 + c1 * w4 + c2 * w5;
                }
                {   // out[p]: dz=0 -> block 1
                    const float c0 = Wsp[wb + 9], c1 = Wsp[wb + 10], c2 = Wsp[wb + 11];
                    A1.x += c0 * w0 + c1 * w1 + c2 * w2;
                    A1.y += c0 * w1 + c1 * w2 + c2 * w3;
                    A1.z += c0 * w2 + c1 * w3 + c2 * w4;
                    A1.w += c0 * w3 + c1 * w4 + c2 * w5;
                }
                {   // out[p+1]: dz=-1 -> block 0
                    const float c0 = Wsp[wb + 0], c1 = Wsp[wb + 1], c2 = Wsp[wb + 2];
                    A2.x += c0 * w0 + c1 * w1 + c2 * w2;
                    A2.y += c0 * w1 + c1 * w2 + c2 * w3;
                    A2.z += c0 * w2 + c1 * w3 + c2 * w4;
                    A2.w += c0 * w3 + c1 * w4 + c2 * w5;
                }
            }
        }
        if (p >= 1) {   // retire out[p-1]
            *reinterpret_cast<float4*>(&g[base + (size_t)(p - 1) * HW + prow]) = A0;
            bnsum += A0.x + A0.y + A0.z + A0.w;
            bnsq += A0.x * A0.x + A0.y * A0.y + A0.z * A0.z + A0.w * A0.w;
        }
        A0 = A1; A1 = A2;
        if (p < 15) {
            *reinterpret_cast<float4*>(&sm[slot ^ 1][0][(u + 1) * 40 + v4 + 4]) = nx;
            *reinterpret_cast<float4*>(&sm[slot ^ 1][1][(u + 1) * 40 + v4 + 4]) = nn;
        }
        __syncthreads();
    }
    // retire out[15] (virtual plane 16 = zero)
    *reinterpret_cast<float4*>(&g[base + (size_t)15 * HW + prow]) = A0;
    bnsum += A0.x + A0.y + A0.z + A0.w;
    bnsq += A0.x * A0.x + A0.y * A0.y + A0.z * A0.z + A0.w * A0.w;

    #pragma unroll
    for (int off = 32; off > 0; off >>= 1) {
        bnsum += __shfl_down(bnsum, off);
        bnsq += __shfl_down(bnsq, off);
    }
    if ((tid & 63) == 0) { red[tid >> 6] = bnsum; red[4 + (tid >> 6)] = bnsq; }
    __syncthreads();
    if (tid == 0) {
        atomicAdd(&stats[ST_BNSUM + o], red[0] + red[1] + red[2] + red[3]);
        atomicAdd(&stats[ST_BNSQ + o], red[4] + red[5] + red[6] + red[7]);
    }
}

// ===== Kernel 3: BN -> sigmoid gate -> caps_next + LN partials (proven) =====
__global__ __launch_bounds__(256) void finalize_kernel(
        const float* __restrict__ g, const float* __restrict__ accm_g,
        const float* __restrict__ wsum_g,
        const float* __restrict__ bn_gamma, const float* __restrict__ bn_beta,
        float* __restrict__ cn, float* __restrict__ stats)
{
    const int d = blockIdx.x & 15;
    const int o = (blockIdx.x >> 4) & 7;
    const int b = blockIdx.x >> 7;
    const int px0 = threadIdx.x * 4;

    const float nbn = 1.f / (float)(BATCH * DOUT * HW);
    const float mu = stats[ST_BNSUM + o] * nbn;
    const float var = fmaxf(stats[ST_BNSQ + o] * nbn - mu * mu, 0.f);
    const float rstd = rsqrtf(var + EPSF);
    const float gam = bn_gamma[0], bet = bn_beta[0];

    const size_t gbase = (((size_t)b * CO + o) * DOUT + d) * HW + px0;
    float4 g4 = *reinterpret_cast<const float4*>(&g[gbase]);
    float4 a4 = *reinterpret_cast<const float4*>(&accm_g[gbase]);
    float4 w4 = *reinterpret_cast<const float4*>(&wsum_g[gbase]);
    float4 cnv;
    cnv.x = (1.f + 1.f / (1.f + expf(-((g4.x - mu) * rstd * gam + bet)))) * a4.x / w4.x;
    cnv.y = (1.f + 1.f / (1.f + expf(-((g4.y - mu) * rstd * gam + bet)))) * a4.y / w4.y;
    cnv.z = (1.f + 1.f / (1.f + expf(-((g4.z - mu) * rstd * gam + bet)))) * a4.z / w4.z;
    cnv.w = (1.f + 1.f / (1.f + expf(-((g4.w - mu) * rstd * gam + bet)))) * a4.w / w4.w;
    *reinterpret_cast<float4*>(&cn[gbase]) = cnv;

    float s = cnv.x + cnv.y + cnv.z + cnv.w;
    float sq = cnv.x * cnv.x + cnv.y * cnv.y + cnv.z * cnv.z + cnv.w * cnv.w;
    wave_reduce_atomic2(s, sq, &stats[ST_LNSUM + b * CO + o], &stats[ST_LNSQ + b * CO + o]);
}

// ===== Kernel 4: LayerNorm + transpose-out (proven) =========================
__global__ __launch_bounds__(256) void ln_kernel(
        const float* __restrict__ cn, const float* __restrict__ stats,
        const float* __restrict__ lng, const float* __restrict__ lnb,
        float* __restrict__ out)
{
    const int bo = blockIdx.x;
    const int b = bo >> 3, o = bo & 7;
    const float nln = 1.f / 16384.f;
    const float mu = stats[ST_LNSUM + bo] * nln;
    const float var = fmaxf(stats[ST_LNSQ + bo] * nln - mu * mu, 0.f);
    const float rstd = rsqrtf(var + EPSF);
    const float* src = cn + (size_t)bo * 16384;
    float* dst = out + ((size_t)o * BATCH + b) * 16384;
    #pragma unroll
    for (int i = 0; i < 16; i++) {
        const int e = i * 1024 + threadIdx.x * 4;
        float4 x = *reinterpret_cast<const float4*>(src + e);
        float4 gm = *reinterpret_cast<const float4*>(lng + e);
        float4 bb = *reinterpret_cast<const float4*>(lnb + e);
        float4 y;
        y.x = (x.x - mu) * rstd * gm.x + bb.x;
        y.y = (x.y - mu) * rstd * gm.y + bb.y;
        y.z = (x.z - mu) * rstd * gm.z + bb.z;
        y.w = (x.w - mu) * rstd * gm.w + bb.w;
        *reinterpret_cast<float4*>(dst + e) = y;
    }
}

extern "C" void kernel_launch(void* const* d_in, const int* in_sizes, int n_in,
                              void* d_out, int out_size, void* d_ws, size_t ws_size,
                              hipStream_t stream) {
    const float* caps = (const float*)d_in[0];
    const float* Wt   = (const float*)d_in[1];
    const float* bt   = (const float*)d_in[2];
    const float* Wv   = (const float*)d_in[3];
    const float* bv   = (const float*)d_in[4];
    const float* Wsp  = (const float*)d_in[5];
    const float* bng  = (const float*)d_in[6];
    const float* bnb  = (const float*)d_in[7];
    const float* lng  = (const float*)d_in[8];
    const float* lnb  = (const float*)d_in[9];
    float* ws = (float*)d_ws;
    float* pmax  = ws + OFF_PMAX;
    float* pmean = ws + OFF_PMEAN;
    float* accm  = ws + OFF_ACCM;
    float* wsum  = ws + OFF_WSUM;
    float* g     = ws + OFF_G;
    float* cn    = ws + OFF_CN;
    float* stats = ws + OFF_STATS;
    ushort* wfrag = (ushort*)(ws + OFF_WFRAG);
    float* out = (float*)d_out;

    hipMemsetAsync(stats, 0, STATS_FLOATS * sizeof(float), stream);
    wfrag_kernel<<<320, 256, 0, stream>>>(Wt, bt, Wv, bv, wfrag);
    convmfma_kernel<<<dim3(16, 32), 256, 0, stream>>>(caps, wfrag, pmax, pmean, accm, wsum);
    stencil_kernel<<<256, 256, 0, stream>>>(pmax, pmean, Wsp, g, stats);
    finalize_kernel<<<4096, 256, 0, stream>>>(g, accm, wsum, bng, bnb, cn, stats);
    ln_kernel<<<256, 256, 0, stream>>>(cn, stats, lng, lnb, out);
}